// Round 1
// baseline (571.795 us; speedup 1.0000x reference)
//
#include <hip/hip_runtime.h>
#include <math.h>

#define N_NODES 50000
#define N_EDGES 400000
#define N_TOT   450000   /* edges + self-loops */
#define NEG 0.2f

__device__ __forceinline__ float lrelu(float x) { return x > 0.f ? x : NEG * x; }

/* ---------------- CSR build (by destination) ---------------- */

__global__ void k_zero(int* p, int n) {
    int i = blockIdx.x * blockDim.x + threadIdx.x;
    if (i < n) p[i] = 0;
}

__global__ void k_hist(const int* ei, int* counts) {
    int i = blockIdx.x * blockDim.x + threadIdx.x;
    if (i >= N_TOT) return;
    int dst = (i < N_EDGES) ? ei[N_EDGES + i] : (i - N_EDGES);
    atomicAdd(&counts[dst], 1);
}

/* block-wise inclusive scan: 256 threads x 4 items = 1024/block */
__global__ void k_scan1(const int* counts, int* rowptr, int* bsums) {
    __shared__ int sh[256];
    int t = threadIdx.x;
    int base = blockIdx.x * 1024;
    int idx0 = base + t * 4;
    int v[4];
#pragma unroll
    for (int i = 0; i < 4; i++) { int idx = idx0 + i; v[i] = (idx < N_NODES) ? counts[idx] : 0; }
    v[1] += v[0]; v[2] += v[1]; v[3] += v[2];
    int incl = v[3];
    sh[t] = incl;
    __syncthreads();
    for (int off = 1; off < 256; off <<= 1) {
        int add = (t >= off) ? sh[t - off] : 0;
        __syncthreads();
        incl += add;
        sh[t] = incl;
        __syncthreads();
    }
    int excl = incl - v[3];
#pragma unroll
    for (int i = 0; i < 4; i++) { int idx = idx0 + i; if (idx < N_NODES) rowptr[idx + 1] = v[i] + excl; }
    if (t == 255) bsums[blockIdx.x] = incl;
}

/* scan of 49 block sums -> exclusive, single wave */
__global__ void k_scan2(int* bsums, int nb) {
    int l = threadIdx.x;
    int v = (l < nb) ? bsums[l] : 0;
    int orig = v;
    for (int off = 1; off < 64; off <<= 1) {
        int u = __shfl_up(v, off, 64);
        if (l >= off) v += u;
    }
    if (l < nb) bsums[l] = v - orig;
}

__global__ void k_scan3(int* rowptr, const int* bsums) {
    int i = blockIdx.x * blockDim.x + threadIdx.x;
    if (i == 0) rowptr[0] = 0;
    if (i < N_NODES) rowptr[i + 1] += bsums[i / 1024];
}

__global__ void k_scatter(const int* ei, const int* rowptr, int* cursor, int* colsrc) {
    int i = blockIdx.x * blockDim.x + threadIdx.x;
    if (i >= N_TOT) return;
    int src, dst;
    if (i < N_EDGES) { src = ei[i]; dst = ei[N_EDGES + i]; }
    else             { src = dst = i - N_EDGES; }
    int pos = rowptr[dst] + atomicAdd(&cursor[dst], 1);
    colsrc[pos] = src;
}

/* ---------------- Layer 1: GEMM [N,128]@[128,512] + attention halves ---------------- */
/* block = 512 threads (8 waves), 32 rows/block; thread owns column t for 32 rows.
   wave w == head w exactly (64 cols per head). */
__global__ __launch_bounds__(512) void k_gemm1(const float* __restrict__ x,
                                               const float* __restrict__ W1,
                                               const float* __restrict__ a1s,
                                               const float* __restrict__ a1d,
                                               float* __restrict__ h1,
                                               float* __restrict__ al1s,
                                               float* __restrict__ al1d) {
    __shared__ __align__(16) float xs[32 * 128];
    int t = threadIdx.x;
    int rowbase = blockIdx.x * 32;
    for (int i = t; i < 32 * 128; i += 512) {
        int r = i >> 7, k = i & 127;
        int gr = rowbase + r;
        xs[i] = (gr < N_NODES) ? x[gr * 128 + k] : 0.f;
    }
    __syncthreads();
    float acc[32];
#pragma unroll
    for (int r = 0; r < 32; r++) acc[r] = 0.f;
    for (int k = 0; k < 128; k += 4) {
        float w0 = W1[(k + 0) * 512 + t];
        float w1 = W1[(k + 1) * 512 + t];
        float w2 = W1[(k + 2) * 512 + t];
        float w3 = W1[(k + 3) * 512 + t];
#pragma unroll
        for (int r = 0; r < 32; r++) {
            const float4 xv = *reinterpret_cast<const float4*>(&xs[r * 128 + k]);
            acc[r] = fmaf(xv.x, w0, acc[r]);
            acc[r] = fmaf(xv.y, w1, acc[r]);
            acc[r] = fmaf(xv.z, w2, acc[r]);
            acc[r] = fmaf(xv.w, w3, acc[r]);
        }
    }
    int lane = t & 63;
    int head = t >> 6;
    float as = a1s[head * 64 + lane];
    float ad = a1d[head * 64 + lane];
#pragma unroll
    for (int r = 0; r < 32; r++) {
        int gr = rowbase + r;
        float v = acc[r];
        if (gr < N_NODES) h1[gr * 512 + t] = v;
        float ps = v * as, pd = v * ad;
#pragma unroll
        for (int off = 32; off; off >>= 1) {
            ps += __shfl_xor(ps, off, 64);
            pd += __shfl_xor(pd, off, 64);
        }
        if (lane == 0 && gr < N_NODES) { al1s[gr * 8 + head] = ps; al1d[gr * 8 + head] = pd; }
    }
}

/* ---------------- Layer 1: softmax + aggregation, one wave per dst node ---------------- */
__global__ __launch_bounds__(256) void k_agg1(const int* __restrict__ rowptr,
                                              const int* __restrict__ colsrc,
                                              const float* __restrict__ al1s,
                                              const float* __restrict__ al1d,
                                              const float* __restrict__ h1,
                                              const float* __restrict__ b1,
                                              float* __restrict__ h1a) {
    int wid = threadIdx.x >> 6;
    int lane = threadIdx.x & 63;
    int n = blockIdx.x * 4 + wid;
    if (n >= N_NODES) return;
    int r0 = rowptr[n], r1 = rowptr[n + 1];
    float ald[8];
#pragma unroll
    for (int h = 0; h < 8; h++) ald[h] = al1d[n * 8 + h];

    /* pass A: per-head max over incoming edges */
    float mx[8];
#pragma unroll
    for (int h = 0; h < 8; h++) mx[h] = -1e30f;
    for (int e = r0 + lane; e < r1; e += 64) {
        int s = colsrc[e];
#pragma unroll
        for (int h = 0; h < 8; h++)
            mx[h] = fmaxf(mx[h], lrelu(al1s[s * 8 + h] + ald[h]));
    }
#pragma unroll
    for (int h = 0; h < 8; h++)
#pragma unroll
        for (int off = 32; off; off >>= 1) mx[h] = fmaxf(mx[h], __shfl_xor(mx[h], off, 64));

    /* pass B: per-head denom */
    float sm[8];
#pragma unroll
    for (int h = 0; h < 8; h++) sm[h] = 0.f;
    for (int e = r0 + lane; e < r1; e += 64) {
        int s = colsrc[e];
#pragma unroll
        for (int h = 0; h < 8; h++)
            sm[h] += __expf(lrelu(al1s[s * 8 + h] + ald[h]) - mx[h]);
    }
#pragma unroll
    for (int h = 0; h < 8; h++) {
#pragma unroll
        for (int off = 32; off; off >>= 1) sm[h] += __shfl_xor(sm[h], off, 64);
    }
    float inv[8];
#pragma unroll
    for (int h = 0; h < 8; h++) inv[h] = 1.f / sm[h];

    /* pass C: weighted aggregation. lane owns channels [4*lane,4*lane+4) (head lane/16)
       and [256+4*lane, ...) (head 4+lane/16). */
    int hA = lane >> 4, hB = hA + 4;
    int cA = 4 * lane, cB = 256 + 4 * lane;
    float aldA = (hA == 0) ? ald[0] : (hA == 1) ? ald[1] : (hA == 2) ? ald[2] : ald[3];
    float aldB = (hA == 0) ? ald[4] : (hA == 1) ? ald[5] : (hA == 2) ? ald[6] : ald[7];
    float mA   = (hA == 0) ? mx[0]  : (hA == 1) ? mx[1]  : (hA == 2) ? mx[2]  : mx[3];
    float mB   = (hA == 0) ? mx[4]  : (hA == 1) ? mx[5]  : (hA == 2) ? mx[6]  : mx[7];
    float iA   = (hA == 0) ? inv[0] : (hA == 1) ? inv[1] : (hA == 2) ? inv[2] : inv[3];
    float iB   = (hA == 0) ? inv[4] : (hA == 1) ? inv[5] : (hA == 2) ? inv[6] : inv[7];
    float4 aA = {0.f, 0.f, 0.f, 0.f}, aB = {0.f, 0.f, 0.f, 0.f};
    for (int e = r0; e < r1; e++) {
        int s = colsrc[e];
        float wA = __expf(lrelu(al1s[s * 8 + hA] + aldA) - mA) * iA;
        float wB = __expf(lrelu(al1s[s * 8 + hB] + aldB) - mB) * iB;
        const float4 fA = *reinterpret_cast<const float4*>(&h1[s * 512 + cA]);
        const float4 fB = *reinterpret_cast<const float4*>(&h1[s * 512 + cB]);
        aA.x = fmaf(wA, fA.x, aA.x); aA.y = fmaf(wA, fA.y, aA.y);
        aA.z = fmaf(wA, fA.z, aA.z); aA.w = fmaf(wA, fA.w, aA.w);
        aB.x = fmaf(wB, fB.x, aB.x); aB.y = fmaf(wB, fB.y, aB.y);
        aB.z = fmaf(wB, fB.z, aB.z); aB.w = fmaf(wB, fB.w, aB.w);
    }
    /* + b1, ELU, store */
    const float4 bA = *reinterpret_cast<const float4*>(&b1[cA]);
    const float4 bB = *reinterpret_cast<const float4*>(&b1[cB]);
    aA.x += bA.x; aA.y += bA.y; aA.z += bA.z; aA.w += bA.w;
    aB.x += bB.x; aB.y += bB.y; aB.z += bB.z; aB.w += bB.w;
    aA.x = aA.x > 0.f ? aA.x : __expf(aA.x) - 1.f;
    aA.y = aA.y > 0.f ? aA.y : __expf(aA.y) - 1.f;
    aA.z = aA.z > 0.f ? aA.z : __expf(aA.z) - 1.f;
    aA.w = aA.w > 0.f ? aA.w : __expf(aA.w) - 1.f;
    aB.x = aB.x > 0.f ? aB.x : __expf(aB.x) - 1.f;
    aB.y = aB.y > 0.f ? aB.y : __expf(aB.y) - 1.f;
    aB.z = aB.z > 0.f ? aB.z : __expf(aB.z) - 1.f;
    aB.w = aB.w > 0.f ? aB.w : __expf(aB.w) - 1.f;
    *reinterpret_cast<float4*>(&h1a[n * 512 + cA]) = aA;
    *reinterpret_cast<float4*>(&h1a[n * 512 + cB]) = aB;
}

/* ---------------- Layer 2: GEMM [N,512]@[512,16] + attention halves ---------------- */
__global__ __launch_bounds__(256) void k_gemm2(const float* __restrict__ h1a,
                                               const float* __restrict__ W2,
                                               const float* __restrict__ a2s,
                                               const float* __restrict__ a2d,
                                               float* __restrict__ h2,
                                               float* __restrict__ al2s,
                                               float* __restrict__ al2d) {
    __shared__ float w2[512 * 16];
    for (int i = threadIdx.x; i < 512 * 16; i += 256) w2[i] = W2[i];
    __syncthreads();
    int wid = threadIdx.x >> 6, lane = threadIdx.x & 63;
    int n = blockIdx.x * 4 + wid;
    if (n >= N_NODES) return;
    int c = lane & 15, q = lane >> 4;
    float acc = 0.f;
    for (int i = 0; i < 128; i++) {
        int k = q + 4 * i;
        acc = fmaf(h1a[n * 512 + k], w2[k * 16 + c], acc);
    }
    acc += __shfl_xor(acc, 16, 64);
    acc += __shfl_xor(acc, 32, 64);
    if (q == 0) h2[n * 16 + c] = acc;
    float ps = acc * a2s[c];
    float pd = acc * a2d[c];
#pragma unroll
    for (int off = 1; off < 16; off <<= 1) {
        ps += __shfl_xor(ps, off, 64);
        pd += __shfl_xor(pd, off, 64);
    }
    if (lane == 0) { al2s[n] = ps; al2d[n] = pd; }
}

/* ---------------- Layer 2: softmax + aggregation + bias -> out ---------------- */
__global__ __launch_bounds__(256) void k_agg2(const int* __restrict__ rowptr,
                                              const int* __restrict__ colsrc,
                                              const float* __restrict__ al2s,
                                              const float* __restrict__ al2d,
                                              const float* __restrict__ h2,
                                              const float* __restrict__ b2,
                                              float* __restrict__ out) {
    int wid = threadIdx.x >> 6, lane = threadIdx.x & 63;
    int n = blockIdx.x * 4 + wid;
    if (n >= N_NODES) return;
    int r0 = rowptr[n], r1 = rowptr[n + 1];
    float ald = al2d[n];
    float mx = -1e30f;
    for (int e = r0 + lane; e < r1; e += 64)
        mx = fmaxf(mx, lrelu(al2s[colsrc[e]] + ald));
#pragma unroll
    for (int off = 32; off; off >>= 1) mx = fmaxf(mx, __shfl_xor(mx, off, 64));
    float sm = 0.f;
    for (int e = r0 + lane; e < r1; e += 64)
        sm += __expf(lrelu(al2s[colsrc[e]] + ald) - mx);
#pragma unroll
    for (int off = 32; off; off >>= 1) sm += __shfl_xor(sm, off, 64);
    float inv = 1.f / sm;
    int c = lane & 15, q = lane >> 4;
    float acc = 0.f;
    for (int e = r0 + q; e < r1; e += 4) {
        int s = colsrc[e];
        float w = __expf(lrelu(al2s[s] + ald) - mx) * inv;
        acc = fmaf(w, h2[s * 16 + c], acc);
    }
    acc += __shfl_xor(acc, 16, 64);
    acc += __shfl_xor(acc, 32, 64);
    if (q == 0) out[n * 16 + c] = acc + b2[c];
}

/* ---------------- launch ---------------- */
extern "C" void kernel_launch(void* const* d_in, const int* in_sizes, int n_in,
                              void* d_out, int out_size, void* d_ws, size_t ws_size,
                              hipStream_t stream) {
    const float* x   = (const float*)d_in[0];
    const int*   ei  = (const int*)d_in[1];
    const float* W1  = (const float*)d_in[2];
    const float* a1s = (const float*)d_in[3];
    const float* a1d = (const float*)d_in[4];
    const float* b1  = (const float*)d_in[5];
    const float* W2  = (const float*)d_in[6];
    const float* a2s = (const float*)d_in[7];
    const float* a2d = (const float*)d_in[8];
    const float* b2  = (const float*)d_in[9];
    float* out = (float*)d_out;

    char* ws = (char*)d_ws;
    float* h1   = (float*)(ws + 0);            /* N*512 f32 = 102.4 MB */
    float* h1a  = (float*)(ws + 102400000);    /* N*512 f32 = 102.4 MB */
    float* h2   = (float*)(ws + 204800000);    /* N*16  f32 */
    float* al1s = (float*)(ws + 208000000);    /* N*8 */
    float* al1d = (float*)(ws + 209600000);    /* N*8 */
    float* al2s = (float*)(ws + 211200000);    /* N */
    float* al2d = (float*)(ws + 211400000);    /* N */
    int* rowptr = (int*)(ws + 211600000);      /* N+1 */
    int* counts = (int*)(ws + 211800004);      /* N */
    int* cursor = (int*)(ws + 212000004);      /* N (contiguous after counts) */
    int* colsrc = (int*)(ws + 212200004);      /* N_TOT */
    int* bsums  = (int*)(ws + 214000004);      /* 49 */

    /* CSR build */
    k_zero<<<(2 * N_NODES + 255) / 256, 256, 0, stream>>>(counts, 2 * N_NODES);
    k_hist<<<(N_TOT + 255) / 256, 256, 0, stream>>>(ei, counts);
    k_scan1<<<49, 256, 0, stream>>>(counts, rowptr, bsums);
    k_scan2<<<1, 64, 0, stream>>>(bsums, 49);
    k_scan3<<<(N_NODES + 255) / 256, 256, 0, stream>>>(rowptr, bsums);
    k_scatter<<<(N_TOT + 255) / 256, 256, 0, stream>>>(ei, rowptr, cursor, colsrc);

    /* layer 1 */
    k_gemm1<<<(N_NODES + 31) / 32, 512, 0, stream>>>(x, W1, a1s, a1d, h1, al1s, al1d);
    k_agg1<<<(N_NODES + 3) / 4, 256, 0, stream>>>(rowptr, colsrc, al1s, al1d, h1, b1, h1a);

    /* layer 2 */
    k_gemm2<<<(N_NODES + 3) / 4, 256, 0, stream>>>(h1a, W2, a2s, a2d, h2, al2s, al2d);
    k_agg2<<<(N_NODES + 3) / 4, 256, 0, stream>>>(rowptr, colsrc, al2s, al2d, h2, b2, out);
}

// Round 2
// 408.700 us; speedup vs baseline: 1.3991x; 1.3991x over previous
//
#include <hip/hip_runtime.h>
#include <math.h>

#define N_NODES 50000
#define N_EDGES 400000
#define N_TOT   450000   /* edges + self-loops */
#define NEG 0.2f

typedef __attribute__((ext_vector_type(8))) short bf16x8;
typedef __attribute__((ext_vector_type(4))) float f32x4;

__device__ __forceinline__ float lrelu(float x) { return x > 0.f ? x : NEG * x; }

__device__ __forceinline__ unsigned short f2bf(float f) {
    unsigned u = __float_as_uint(f);
    unsigned r = u + 0x7FFFu + ((u >> 16) & 1u);   /* RNE */
    return (unsigned short)(r >> 16);
}
__device__ __forceinline__ float bf2f(unsigned short h) {
    return __uint_as_float(((unsigned)h) << 16);
}

/* ---------------- CSR build (by destination) ---------------- */

__global__ void k_zero(int* p, int n) {
    int i = blockIdx.x * blockDim.x + threadIdx.x;
    if (i < n) p[i] = 0;
}

__global__ void k_hist(const int* ei, int* counts) {
    int i = blockIdx.x * blockDim.x + threadIdx.x;
    if (i >= N_TOT) return;
    int dst = (i < N_EDGES) ? ei[N_EDGES + i] : (i - N_EDGES);
    atomicAdd(&counts[dst], 1);
}

__global__ void k_scan1(const int* counts, int* rowptr, int* bsums) {
    __shared__ int sh[256];
    int t = threadIdx.x;
    int base = blockIdx.x * 1024;
    int idx0 = base + t * 4;
    int v[4];
#pragma unroll
    for (int i = 0; i < 4; i++) { int idx = idx0 + i; v[i] = (idx < N_NODES) ? counts[idx] : 0; }
    v[1] += v[0]; v[2] += v[1]; v[3] += v[2];
    int incl = v[3];
    sh[t] = incl;
    __syncthreads();
    for (int off = 1; off < 256; off <<= 1) {
        int add = (t >= off) ? sh[t - off] : 0;
        __syncthreads();
        incl += add;
        sh[t] = incl;
        __syncthreads();
    }
    int excl = incl - v[3];
#pragma unroll
    for (int i = 0; i < 4; i++) { int idx = idx0 + i; if (idx < N_NODES) rowptr[idx + 1] = v[i] + excl; }
    if (t == 255) bsums[blockIdx.x] = incl;
}

__global__ void k_scan2(int* bsums, int nb) {
    int l = threadIdx.x;
    int v = (l < nb) ? bsums[l] : 0;
    int orig = v;
    for (int off = 1; off < 64; off <<= 1) {
        int u = __shfl_up(v, off, 64);
        if (l >= off) v += u;
    }
    if (l < nb) bsums[l] = v - orig;
}

__global__ void k_scan3(int* rowptr, const int* bsums) {
    int i = blockIdx.x * blockDim.x + threadIdx.x;
    if (i == 0) rowptr[0] = 0;
    if (i < N_NODES) rowptr[i + 1] += bsums[i / 1024];
}

__global__ void k_scatter(const int* ei, const int* rowptr, int* cursor, int* colsrc) {
    int i = blockIdx.x * blockDim.x + threadIdx.x;
    if (i >= N_TOT) return;
    int src, dst;
    if (i < N_EDGES) { src = ei[i]; dst = ei[N_EDGES + i]; }
    else             { src = dst = i - N_EDGES; }
    int pos = rowptr[dst] + atomicAdd(&cursor[dst], 1);
    colsrc[pos] = src;
}

/* ---------------- Layer 1 GEMM via split-bf16 MFMA ----------------
   grid (782, 8): 64 rows x 64 cols per block, 4 waves, wave w owns cols
   [by*64 + 16w, +16). x staged hi/lo bf16 in LDS (row pad +8 -> 2-way banks).
   W1 fragments converted on the fly (L2-hot), held in VGPRs across m-tiles. */
__global__ __launch_bounds__(256) void k_gemm1(const float* __restrict__ x,
                                               const float* __restrict__ W1,
                                               float* __restrict__ h1) {
    __shared__ unsigned short xs_hi[64 * 136];
    __shared__ unsigned short xs_lo[64 * 136];
    const int t = threadIdx.x;
    const int rb = blockIdx.x * 64;
    const int cb = blockIdx.y * 64;

    /* stage x[rb..rb+64, 0..128] as hi/lo bf16 */
#pragma unroll
    for (int i = 0; i < 8; i++) {
        int idx = t + 256 * i;           /* 2048 float4 total */
        int r = idx >> 5;                /* 32 float4 per row */
        int k = (idx & 31) * 4;
        int gr = rb + r;
        float4 v = make_float4(0.f, 0.f, 0.f, 0.f);
        if (gr < N_NODES) v = *reinterpret_cast<const float4*>(&x[gr * 128 + k]);
        ushort4 hi, lo;
        hi.x = f2bf(v.x); lo.x = f2bf(v.x - bf2f(hi.x));
        hi.y = f2bf(v.y); lo.y = f2bf(v.y - bf2f(hi.y));
        hi.z = f2bf(v.z); lo.z = f2bf(v.z - bf2f(hi.z));
        hi.w = f2bf(v.w); lo.w = f2bf(v.w - bf2f(hi.w));
        *reinterpret_cast<ushort4*>(&xs_hi[r * 136 + k]) = hi;
        *reinterpret_cast<ushort4*>(&xs_lo[r * 136 + k]) = lo;
    }
    __syncthreads();

    const int lane = t & 63;
    const int w = t >> 6;
    const int col = cb + (w << 4) + (lane & 15);
    const int kbase = (lane >> 4) * 8;

    /* build B fragments for this wave's 16 columns, all K (4 chunks of 32) */
    bf16x8 bhi[4], blo[4];
#pragma unroll
    for (int kc = 0; kc < 4; kc++) {
#pragma unroll
        for (int j = 0; j < 8; j++) {
            float wv = W1[(kc * 32 + kbase + j) * 512 + col];
            unsigned short h = f2bf(wv);
            bhi[kc][j] = (short)h;
            blo[kc][j] = (short)f2bf(wv - bf2f(h));
        }
    }

#pragma unroll
    for (int mt = 0; mt < 4; mt++) {
        f32x4 acc = {0.f, 0.f, 0.f, 0.f};
        const int arow = mt * 16 + (lane & 15);
#pragma unroll
        for (int kc = 0; kc < 4; kc++) {
            bf16x8 ah = *reinterpret_cast<const bf16x8*>(&xs_hi[arow * 136 + kc * 32 + kbase]);
            bf16x8 al = *reinterpret_cast<const bf16x8*>(&xs_lo[arow * 136 + kc * 32 + kbase]);
            acc = __builtin_amdgcn_mfma_f32_16x16x32_bf16(ah, bhi[kc], acc, 0, 0, 0);
            acc = __builtin_amdgcn_mfma_f32_16x16x32_bf16(ah, blo[kc], acc, 0, 0, 0);
            acc = __builtin_amdgcn_mfma_f32_16x16x32_bf16(al, bhi[kc], acc, 0, 0, 0);
        }
        const int r0 = rb + mt * 16 + (lane >> 4) * 4;
#pragma unroll
        for (int r = 0; r < 4; r++) {
            int row = r0 + r;
            if (row < N_NODES) h1[row * 512 + col] = acc[r];
        }
    }
}

/* ---------------- attention halves, layer 1: al = einsum(h1, a) ---------------- */
__global__ __launch_bounds__(256) void k_att1(const float* __restrict__ h1,
                                              const float* __restrict__ a1s,
                                              const float* __restrict__ a1d,
                                              float* __restrict__ al1s,
                                              float* __restrict__ al1d) {
    int wid = threadIdx.x >> 6, lane = threadIdx.x & 63;
    int n = blockIdx.x * 4 + wid;
    if (n >= N_NODES) return;
    int head = lane >> 3;
    int ch0 = (lane & 7) * 8;
    const float4 s0 = *reinterpret_cast<const float4*>(&a1s[head * 64 + ch0]);
    const float4 s1 = *reinterpret_cast<const float4*>(&a1s[head * 64 + ch0 + 4]);
    const float4 d0 = *reinterpret_cast<const float4*>(&a1d[head * 64 + ch0]);
    const float4 d1 = *reinterpret_cast<const float4*>(&a1d[head * 64 + ch0 + 4]);
    const float4 h0 = *reinterpret_cast<const float4*>(&h1[n * 512 + lane * 8]);
    const float4 h4 = *reinterpret_cast<const float4*>(&h1[n * 512 + lane * 8 + 4]);
    float ps = h0.x * s0.x + h0.y * s0.y + h0.z * s0.z + h0.w * s0.w
             + h4.x * s1.x + h4.y * s1.y + h4.z * s1.z + h4.w * s1.w;
    float pd = h0.x * d0.x + h0.y * d0.y + h0.z * d0.z + h0.w * d0.w
             + h4.x * d1.x + h4.y * d1.y + h4.z * d1.z + h4.w * d1.w;
#pragma unroll
    for (int off = 1; off < 8; off <<= 1) {
        ps += __shfl_xor(ps, off, 64);
        pd += __shfl_xor(pd, off, 64);
    }
    if ((lane & 7) == 0) {
        al1s[n * 8 + head] = ps;
        al1d[n * 8 + head] = pd;
    }
}

/* ---------------- Layer 1: softmax + aggregation, one wave per dst node ---------------- */
__global__ __launch_bounds__(256) void k_agg1(const int* __restrict__ rowptr,
                                              const int* __restrict__ colsrc,
                                              const float* __restrict__ al1s,
                                              const float* __restrict__ al1d,
                                              const float* __restrict__ h1,
                                              const float* __restrict__ b1,
                                              float* __restrict__ h1a) {
    int wid = threadIdx.x >> 6;
    int lane = threadIdx.x & 63;
    int n = blockIdx.x * 4 + wid;
    if (n >= N_NODES) return;
    int r0 = rowptr[n], r1 = rowptr[n + 1];
    float ald[8];
#pragma unroll
    for (int h = 0; h < 8; h++) ald[h] = al1d[n * 8 + h];

    float mx[8];
#pragma unroll
    for (int h = 0; h < 8; h++) mx[h] = -1e30f;
    for (int e = r0 + lane; e < r1; e += 64) {
        int s = colsrc[e];
#pragma unroll
        for (int h = 0; h < 8; h++)
            mx[h] = fmaxf(mx[h], lrelu(al1s[s * 8 + h] + ald[h]));
    }
#pragma unroll
    for (int h = 0; h < 8; h++)
#pragma unroll
        for (int off = 32; off; off >>= 1) mx[h] = fmaxf(mx[h], __shfl_xor(mx[h], off, 64));

    float sm[8];
#pragma unroll
    for (int h = 0; h < 8; h++) sm[h] = 0.f;
    for (int e = r0 + lane; e < r1; e += 64) {
        int s = colsrc[e];
#pragma unroll
        for (int h = 0; h < 8; h++)
            sm[h] += __expf(lrelu(al1s[s * 8 + h] + ald[h]) - mx[h]);
    }
#pragma unroll
    for (int h = 0; h < 8; h++) {
#pragma unroll
        for (int off = 32; off; off >>= 1) sm[h] += __shfl_xor(sm[h], off, 64);
    }
    float inv[8];
#pragma unroll
    for (int h = 0; h < 8; h++) inv[h] = 1.f / sm[h];

    int hA = lane >> 4, hB = hA + 4;
    int cA = 4 * lane, cB = 256 + 4 * lane;
    float aldA = (hA == 0) ? ald[0] : (hA == 1) ? ald[1] : (hA == 2) ? ald[2] : ald[3];
    float aldB = (hA == 0) ? ald[4] : (hA == 1) ? ald[5] : (hA == 2) ? ald[6] : ald[7];
    float mA   = (hA == 0) ? mx[0]  : (hA == 1) ? mx[1]  : (hA == 2) ? mx[2]  : mx[3];
    float mB   = (hA == 0) ? mx[4]  : (hA == 1) ? mx[5]  : (hA == 2) ? mx[6]  : mx[7];
    float iA   = (hA == 0) ? inv[0] : (hA == 1) ? inv[1] : (hA == 2) ? inv[2] : inv[3];
    float iB   = (hA == 0) ? inv[4] : (hA == 1) ? inv[5] : (hA == 2) ? inv[6] : inv[7];
    float4 aA = {0.f, 0.f, 0.f, 0.f}, aB = {0.f, 0.f, 0.f, 0.f};
    for (int e = r0; e < r1; e++) {
        int s = colsrc[e];
        float wA = __expf(lrelu(al1s[s * 8 + hA] + aldA) - mA) * iA;
        float wB = __expf(lrelu(al1s[s * 8 + hB] + aldB) - mB) * iB;
        const float4 fA = *reinterpret_cast<const float4*>(&h1[s * 512 + cA]);
        const float4 fB = *reinterpret_cast<const float4*>(&h1[s * 512 + cB]);
        aA.x = fmaf(wA, fA.x, aA.x); aA.y = fmaf(wA, fA.y, aA.y);
        aA.z = fmaf(wA, fA.z, aA.z); aA.w = fmaf(wA, fA.w, aA.w);
        aB.x = fmaf(wB, fB.x, aB.x); aB.y = fmaf(wB, fB.y, aB.y);
        aB.z = fmaf(wB, fB.z, aB.z); aB.w = fmaf(wB, fB.w, aB.w);
    }
    const float4 bA = *reinterpret_cast<const float4*>(&b1[cA]);
    const float4 bB = *reinterpret_cast<const float4*>(&b1[cB]);
    aA.x += bA.x; aA.y += bA.y; aA.z += bA.z; aA.w += bA.w;
    aB.x += bB.x; aB.y += bB.y; aB.z += bB.z; aB.w += bB.w;
    aA.x = aA.x > 0.f ? aA.x : __expf(aA.x) - 1.f;
    aA.y = aA.y > 0.f ? aA.y : __expf(aA.y) - 1.f;
    aA.z = aA.z > 0.f ? aA.z : __expf(aA.z) - 1.f;
    aA.w = aA.w > 0.f ? aA.w : __expf(aA.w) - 1.f;
    aB.x = aB.x > 0.f ? aB.x : __expf(aB.x) - 1.f;
    aB.y = aB.y > 0.f ? aB.y : __expf(aB.y) - 1.f;
    aB.z = aB.z > 0.f ? aB.z : __expf(aB.z) - 1.f;
    aB.w = aB.w > 0.f ? aB.w : __expf(aB.w) - 1.f;
    *reinterpret_cast<float4*>(&h1a[n * 512 + cA]) = aA;
    *reinterpret_cast<float4*>(&h1a[n * 512 + cB]) = aB;
}

/* ---------------- Layer 2 GEMM via MFMA: [N,512]@[512,16] ----------------
   128 threads (2 waves), 32 rows/block; wave w owns rows [w*16,+16).
   A(h1a) staged hi-bf16 only in LDS; W2 split hi/lo on the fly. */
__global__ __launch_bounds__(128) void k_gemm2(const float* __restrict__ h1a,
                                               const float* __restrict__ W2,
                                               float* __restrict__ h2) {
    __shared__ unsigned short as_hi[32 * 520];
    const int t = threadIdx.x;
    const int rb = blockIdx.x * 32;

#pragma unroll
    for (int i = 0; i < 32; i++) {
        int idx = t + 128 * i;           /* 4096 float4 total */
        int r = idx >> 7;                /* 128 float4 per row */
        int k = (idx & 127) * 4;
        int gr = rb + r;
        float4 v = make_float4(0.f, 0.f, 0.f, 0.f);
        if (gr < N_NODES) v = *reinterpret_cast<const float4*>(&h1a[gr * 512 + k]);
        ushort4 hi;
        hi.x = f2bf(v.x); hi.y = f2bf(v.y); hi.z = f2bf(v.z); hi.w = f2bf(v.w);
        *reinterpret_cast<ushort4*>(&as_hi[r * 520 + k]) = hi;
    }
    __syncthreads();

    const int lane = t & 63;
    const int w = t >> 6;
    const int col = lane & 15;
    const int kbase = (lane >> 4) * 8;
    const int arow = (w << 4) + (lane & 15);

    f32x4 acc = {0.f, 0.f, 0.f, 0.f};
#pragma unroll
    for (int kc = 0; kc < 16; kc++) {
        bf16x8 bh, bl;
#pragma unroll
        for (int j = 0; j < 8; j++) {
            float wv = W2[(kc * 32 + kbase + j) * 16 + col];
            unsigned short h = f2bf(wv);
            bh[j] = (short)h;
            bl[j] = (short)f2bf(wv - bf2f(h));
        }
        bf16x8 ah = *reinterpret_cast<const bf16x8*>(&as_hi[arow * 520 + kc * 32 + kbase]);
        acc = __builtin_amdgcn_mfma_f32_16x16x32_bf16(ah, bh, acc, 0, 0, 0);
        acc = __builtin_amdgcn_mfma_f32_16x16x32_bf16(ah, bl, acc, 0, 0, 0);
    }
    const int r0 = rb + (w << 4) + (lane >> 4) * 4;
#pragma unroll
    for (int r = 0; r < 4; r++) {
        int row = r0 + r;
        if (row < N_NODES) h2[row * 16 + col] = acc[r];
    }
}

/* ---------------- attention halves, layer 2 ---------------- */
__global__ __launch_bounds__(256) void k_att2(const float* __restrict__ h2,
                                              const float* __restrict__ a2s,
                                              const float* __restrict__ a2d,
                                              float* __restrict__ al2s,
                                              float* __restrict__ al2d) {
    int n = blockIdx.x * blockDim.x + threadIdx.x;
    if (n >= N_NODES) return;
    float ps = 0.f, pd = 0.f;
#pragma unroll
    for (int j = 0; j < 16; j++) {
        float v = h2[n * 16 + j];
        ps = fmaf(v, a2s[j], ps);
        pd = fmaf(v, a2d[j], pd);
    }
    al2s[n] = ps;
    al2d[n] = pd;
}

/* ---------------- Layer 2: softmax + aggregation + bias -> out ---------------- */
__global__ __launch_bounds__(256) void k_agg2(const int* __restrict__ rowptr,
                                              const int* __restrict__ colsrc,
                                              const float* __restrict__ al2s,
                                              const float* __restrict__ al2d,
                                              const float* __restrict__ h2,
                                              const float* __restrict__ b2,
                                              float* __restrict__ out) {
    int wid = threadIdx.x >> 6, lane = threadIdx.x & 63;
    int n = blockIdx.x * 4 + wid;
    if (n >= N_NODES) return;
    int r0 = rowptr[n], r1 = rowptr[n + 1];
    float ald = al2d[n];
    float mx = -1e30f;
    for (int e = r0 + lane; e < r1; e += 64)
        mx = fmaxf(mx, lrelu(al2s[colsrc[e]] + ald));
#pragma unroll
    for (int off = 32; off; off >>= 1) mx = fmaxf(mx, __shfl_xor(mx, off, 64));
    float sm = 0.f;
    for (int e = r0 + lane; e < r1; e += 64)
        sm += __expf(lrelu(al2s[colsrc[e]] + ald) - mx);
#pragma unroll
    for (int off = 32; off; off >>= 1) sm += __shfl_xor(sm, off, 64);
    float inv = 1.f / sm;
    int c = lane & 15, q = lane >> 4;
    float acc = 0.f;
    for (int e = r0 + q; e < r1; e += 4) {
        int s = colsrc[e];
        float w = __expf(lrelu(al2s[s] + ald) - mx) * inv;
        acc = fmaf(w, h2[s * 16 + c], acc);
    }
    acc += __shfl_xor(acc, 16, 64);
    acc += __shfl_xor(acc, 32, 64);
    if (q == 0) out[n * 16 + c] = acc + b2[c];
}

/* ---------------- launch ---------------- */
extern "C" void kernel_launch(void* const* d_in, const int* in_sizes, int n_in,
                              void* d_out, int out_size, void* d_ws, size_t ws_size,
                              hipStream_t stream) {
    const float* x   = (const float*)d_in[0];
    const int*   ei  = (const int*)d_in[1];
    const float* W1  = (const float*)d_in[2];
    const float* a1s = (const float*)d_in[3];
    const float* a1d = (const float*)d_in[4];
    const float* b1  = (const float*)d_in[5];
    const float* W2  = (const float*)d_in[6];
    const float* a2s = (const float*)d_in[7];
    const float* a2d = (const float*)d_in[8];
    const float* b2  = (const float*)d_in[9];
    float* out = (float*)d_out;

    char* ws = (char*)d_ws;
    float* h1   = (float*)(ws + 0);            /* N*512 f32 = 102.4 MB */
    float* h1a  = (float*)(ws + 102400000);    /* N*512 f32 = 102.4 MB */
    float* h2   = (float*)(ws + 204800000);    /* N*16  f32 */
    float* al1s = (float*)(ws + 208000000);    /* N*8 */
    float* al1d = (float*)(ws + 209600000);    /* N*8 */
    float* al2s = (float*)(ws + 211200000);    /* N */
    float* al2d = (float*)(ws + 211400000);    /* N */
    int* rowptr = (int*)(ws + 211600000);      /* N+1 */
    int* counts = (int*)(ws + 211800004);      /* N */
    int* cursor = (int*)(ws + 212000004);      /* N (contiguous after counts) */
    int* colsrc = (int*)(ws + 212200004);      /* N_TOT */
    int* bsums  = (int*)(ws + 214000004);      /* 49 */

    /* CSR build */
    k_zero<<<(2 * N_NODES + 255) / 256, 256, 0, stream>>>(counts, 2 * N_NODES);
    k_hist<<<(N_TOT + 255) / 256, 256, 0, stream>>>(ei, counts);
    k_scan1<<<49, 256, 0, stream>>>(counts, rowptr, bsums);
    k_scan2<<<1, 64, 0, stream>>>(bsums, 49);
    k_scan3<<<(N_NODES + 255) / 256, 256, 0, stream>>>(rowptr, bsums);
    k_scatter<<<(N_TOT + 255) / 256, 256, 0, stream>>>(ei, rowptr, cursor, colsrc);

    /* layer 1 */
    k_gemm1<<<dim3(782, 8), 256, 0, stream>>>(x, W1, h1);
    k_att1<<<(N_NODES + 3) / 4, 256, 0, stream>>>(h1, a1s, a1d, al1s, al1d);
    k_agg1<<<(N_NODES + 3) / 4, 256, 0, stream>>>(rowptr, colsrc, al1s, al1d, h1, b1, h1a);

    /* layer 2 */
    k_gemm2<<<(N_NODES + 31) / 32, 128, 0, stream>>>(h1a, W2, h2);
    k_att2<<<(N_NODES + 255) / 256, 256, 0, stream>>>(h2, a2s, a2d, al2s, al2d);
    k_agg2<<<(N_NODES + 3) / 4, 256, 0, stream>>>(rowptr, colsrc, al2s, al2d, h2, b2, out);
}

// Round 3
// 316.025 us; speedup vs baseline: 1.8093x; 1.2932x over previous
//
#include <hip/hip_runtime.h>
#include <math.h>

#define N_NODES 50000
#define N_EDGES 400000
#define N_TOT   450000   /* edges + self-loops */
#define NEG 0.2f

typedef __attribute__((ext_vector_type(8))) short bf16x8;
typedef __attribute__((ext_vector_type(4))) float f32x4;

__device__ __forceinline__ float lrelu(float x) { return x > 0.f ? x : NEG * x; }

__device__ __forceinline__ unsigned short f2bf(float f) {
    unsigned u = __float_as_uint(f);
    unsigned r = u + 0x7FFFu + ((u >> 16) & 1u);   /* RNE */
    return (unsigned short)(r >> 16);
}
__device__ __forceinline__ float bf2f(unsigned short h) {
    return __uint_as_float(((unsigned)h) << 16);
}

/* ---------------- CSR build (by destination) ---------------- */

__global__ void k_zero(int* p, int n) {
    int i = blockIdx.x * blockDim.x + threadIdx.x;
    if (i < n) p[i] = 0;
}

__global__ void k_hist(const int* ei, int* counts) {
    int i = blockIdx.x * blockDim.x + threadIdx.x;
    if (i >= N_TOT) return;
    int dst = (i < N_EDGES) ? ei[N_EDGES + i] : (i - N_EDGES);
    atomicAdd(&counts[dst], 1);
}

__global__ void k_scan1(const int* counts, int* rowptr, int* bsums) {
    __shared__ int sh[256];
    int t = threadIdx.x;
    int base = blockIdx.x * 1024;
    int idx0 = base + t * 4;
    int v[4];
#pragma unroll
    for (int i = 0; i < 4; i++) { int idx = idx0 + i; v[i] = (idx < N_NODES) ? counts[idx] : 0; }
    v[1] += v[0]; v[2] += v[1]; v[3] += v[2];
    int incl = v[3];
    sh[t] = incl;
    __syncthreads();
    for (int off = 1; off < 256; off <<= 1) {
        int add = (t >= off) ? sh[t - off] : 0;
        __syncthreads();
        incl += add;
        sh[t] = incl;
        __syncthreads();
    }
    int excl = incl - v[3];
#pragma unroll
    for (int i = 0; i < 4; i++) { int idx = idx0 + i; if (idx < N_NODES) rowptr[idx + 1] = v[i] + excl; }
    if (t == 255) bsums[blockIdx.x] = incl;
}

__global__ void k_scan2(int* bsums, int nb) {
    int l = threadIdx.x;
    int v = (l < nb) ? bsums[l] : 0;
    int orig = v;
    for (int off = 1; off < 64; off <<= 1) {
        int u = __shfl_up(v, off, 64);
        if (l >= off) v += u;
    }
    if (l < nb) bsums[l] = v - orig;
}

__global__ void k_scan3(int* rowptr, const int* bsums) {
    int i = blockIdx.x * blockDim.x + threadIdx.x;
    if (i == 0) rowptr[0] = 0;
    if (i < N_NODES) rowptr[i + 1] += bsums[i / 1024];
}

__global__ void k_scatter(const int* ei, const int* rowptr, int* cursor, int* colsrc) {
    int i = blockIdx.x * blockDim.x + threadIdx.x;
    if (i >= N_TOT) return;
    int src, dst;
    if (i < N_EDGES) { src = ei[i]; dst = ei[N_EDGES + i]; }
    else             { src = dst = i - N_EDGES; }
    int pos = rowptr[dst] + atomicAdd(&cursor[dst], 1);
    colsrc[pos] = src;
}

/* ---------------- weight pre-split: fp32 -> transposed bf16 hi/lo ---------------- */

__global__ void k_prepW1(const float* __restrict__ W1, unsigned short* hiT, unsigned short* loT) {
    int i = blockIdx.x * 256 + threadIdx.x;   /* 65536 = 128k x 512n */
    if (i >= 128 * 512) return;
    int col = i & 511, k = i >> 9;
    float v = W1[k * 512 + col];
    unsigned short h = f2bf(v);
    hiT[col * 128 + k] = h;
    loT[col * 128 + k] = f2bf(v - bf2f(h));
}

__global__ void k_prepW2(const float* __restrict__ W2, unsigned short* hiT, unsigned short* loT) {
    int i = blockIdx.x * 256 + threadIdx.x;   /* 8192 = 512k x 16n */
    if (i >= 512 * 16) return;
    int col = i & 15, k = i >> 4;
    float v = W2[k * 16 + col];
    unsigned short h = f2bf(v);
    hiT[col * 512 + k] = h;
    loT[col * 512 + k] = f2bf(v - bf2f(h));
}

/* ---------------- Layer 1 GEMM via split-bf16 MFMA ----------------
   782 blocks x 256 thr: 64 rows x 512 cols per block (x staged ONCE).
   Strips of 64 cols; B fragments cached per strip-pair; A fragments per m-tile.
   Output h1b written as bf16. */
__global__ __launch_bounds__(256) void k_gemm1(const float* __restrict__ x,
                                               const unsigned short* __restrict__ W1hiT,
                                               const unsigned short* __restrict__ W1loT,
                                               unsigned short* __restrict__ h1b) {
    __shared__ unsigned short xs_hi[64 * 136];
    __shared__ unsigned short xs_lo[64 * 136];
    const int t = threadIdx.x;
    const int rb = blockIdx.x * 64;

    /* stage x[rb..rb+64, 0..128] as hi/lo bf16 */
#pragma unroll
    for (int i = 0; i < 8; i++) {
        int idx = t + 256 * i;           /* 2048 float4 total */
        int r = idx >> 5;                /* 32 float4 per row */
        int k = (idx & 31) * 4;
        int gr = rb + r;
        float4 v = make_float4(0.f, 0.f, 0.f, 0.f);
        if (gr < N_NODES) v = *reinterpret_cast<const float4*>(&x[gr * 128 + k]);
        ushort4 hi, lo;
        hi.x = f2bf(v.x); lo.x = f2bf(v.x - bf2f(hi.x));
        hi.y = f2bf(v.y); lo.y = f2bf(v.y - bf2f(hi.y));
        hi.z = f2bf(v.z); lo.z = f2bf(v.z - bf2f(hi.z));
        hi.w = f2bf(v.w); lo.w = f2bf(v.w - bf2f(hi.w));
        *reinterpret_cast<ushort4*>(&xs_hi[r * 136 + k]) = hi;
        *reinterpret_cast<ushort4*>(&xs_lo[r * 136 + k]) = lo;
    }
    __syncthreads();

    const int lane = t & 63;
    const int w = t >> 6;
    const int kbase = (lane >> 4) * 8;
    const int colloc = (w << 4) + (lane & 15);

#pragma unroll
    for (int pr = 0; pr < 4; pr++) {
        bf16x8 bhi[2][4], blo[2][4];
#pragma unroll
        for (int si = 0; si < 2; si++) {
            int col = (pr * 2 + si) * 64 + colloc;
#pragma unroll
            for (int kc = 0; kc < 4; kc++) {
                bhi[si][kc] = *reinterpret_cast<const bf16x8*>(&W1hiT[col * 128 + kc * 32 + kbase]);
                blo[si][kc] = *reinterpret_cast<const bf16x8*>(&W1loT[col * 128 + kc * 32 + kbase]);
            }
        }
#pragma unroll
        for (int mt = 0; mt < 4; mt++) {
            const int arow = mt * 16 + (lane & 15);
            bf16x8 ah[4], al[4];
#pragma unroll
            for (int kc = 0; kc < 4; kc++) {
                ah[kc] = *reinterpret_cast<const bf16x8*>(&xs_hi[arow * 136 + kc * 32 + kbase]);
                al[kc] = *reinterpret_cast<const bf16x8*>(&xs_lo[arow * 136 + kc * 32 + kbase]);
            }
#pragma unroll
            for (int si = 0; si < 2; si++) {
                f32x4 acc = {0.f, 0.f, 0.f, 0.f};
#pragma unroll
                for (int kc = 0; kc < 4; kc++) {
                    acc = __builtin_amdgcn_mfma_f32_16x16x32_bf16(ah[kc], bhi[si][kc], acc, 0, 0, 0);
                    acc = __builtin_amdgcn_mfma_f32_16x16x32_bf16(ah[kc], blo[si][kc], acc, 0, 0, 0);
                    acc = __builtin_amdgcn_mfma_f32_16x16x32_bf16(al[kc], bhi[si][kc], acc, 0, 0, 0);
                }
                const int col = (pr * 2 + si) * 64 + colloc;
                const int r0 = rb + mt * 16 + (lane >> 4) * 4;
#pragma unroll
                for (int r = 0; r < 4; r++) {
                    int row = r0 + r;
                    if (row < N_NODES) h1b[row * 512 + col] = f2bf(acc[r]);
                }
            }
        }
    }
}

/* ---------------- attention halves, layer 1: al = einsum(h1, a) ---------------- */
__global__ __launch_bounds__(256) void k_att1(const unsigned short* __restrict__ h1b,
                                              const float* __restrict__ a1s,
                                              const float* __restrict__ a1d,
                                              float* __restrict__ al1s,
                                              float* __restrict__ al1d) {
    int wid = threadIdx.x >> 6, lane = threadIdx.x & 63;
    int n = blockIdx.x * 4 + wid;
    if (n >= N_NODES) return;
    int head = lane >> 3;
    int ch0 = (lane & 7) * 8;
    const float4 s0 = *reinterpret_cast<const float4*>(&a1s[head * 64 + ch0]);
    const float4 s1 = *reinterpret_cast<const float4*>(&a1s[head * 64 + ch0 + 4]);
    const float4 d0 = *reinterpret_cast<const float4*>(&a1d[head * 64 + ch0]);
    const float4 d1 = *reinterpret_cast<const float4*>(&a1d[head * 64 + ch0 + 4]);
    ushort4 hv0 = *reinterpret_cast<const ushort4*>(&h1b[n * 512 + lane * 8]);
    ushort4 hv1 = *reinterpret_cast<const ushort4*>(&h1b[n * 512 + lane * 8 + 4]);
    float ps = bf2f(hv0.x) * s0.x + bf2f(hv0.y) * s0.y + bf2f(hv0.z) * s0.z + bf2f(hv0.w) * s0.w
             + bf2f(hv1.x) * s1.x + bf2f(hv1.y) * s1.y + bf2f(hv1.z) * s1.z + bf2f(hv1.w) * s1.w;
    float pd = bf2f(hv0.x) * d0.x + bf2f(hv0.y) * d0.y + bf2f(hv0.z) * d0.z + bf2f(hv0.w) * d0.w
             + bf2f(hv1.x) * d1.x + bf2f(hv1.y) * d1.y + bf2f(hv1.z) * d1.z + bf2f(hv1.w) * d1.w;
#pragma unroll
    for (int off = 1; off < 8; off <<= 1) {
        ps += __shfl_xor(ps, off, 64);
        pd += __shfl_xor(pd, off, 64);
    }
    if ((lane & 7) == 0) {
        al1s[n * 8 + head] = ps;
        al1d[n * 8 + head] = pd;
    }
}

/* ---------------- Layer 1: softmax + aggregation, one wave per dst node ----------------
   Chunks of 64 edges: lane computes the 8 head-logits for ONE edge (single al1s
   gather), exp once, weights stored head-major in LDS (conflict-free broadcast
   reads). No max-subtraction (logits O(7), clamped at 60). */
__global__ __launch_bounds__(256) void k_agg1(const int* __restrict__ rowptr,
                                              const int* __restrict__ colsrc,
                                              const float* __restrict__ al1s,
                                              const float* __restrict__ al1d,
                                              const unsigned short* __restrict__ h1b,
                                              const float* __restrict__ b1,
                                              unsigned short* __restrict__ h1a) {
    __shared__ float pw[4][512];
    int wid = threadIdx.x >> 6;
    int lane = threadIdx.x & 63;
    int n = blockIdx.x * 4 + wid;
    if (n >= N_NODES) return;
    int r0 = rowptr[n], r1 = rowptr[n + 1];
    const float4 d0 = *reinterpret_cast<const float4*>(&al1d[n * 8]);
    const float4 d1 = *reinterpret_cast<const float4*>(&al1d[n * 8 + 4]);
    int hA = lane >> 4, hB = hA + 4;
    int cA = 4 * lane, cB = 256 + 4 * lane;
    f32x4 accA = {0.f, 0.f, 0.f, 0.f}, accB = {0.f, 0.f, 0.f, 0.f};
    float sA = 0.f, sB = 0.f;
    float* mypw = &pw[wid][0];

    for (int base = r0; base < r1; base += 64) {
        int e = base + lane;
        int s0 = 0;
        float p[8];
        if (e < r1) {
            s0 = colsrc[e];
            const float4 u0 = *reinterpret_cast<const float4*>(&al1s[s0 * 8]);
            const float4 u1 = *reinterpret_cast<const float4*>(&al1s[s0 * 8 + 4]);
            p[0] = __expf(fminf(lrelu(u0.x + d0.x), 60.f));
            p[1] = __expf(fminf(lrelu(u0.y + d0.y), 60.f));
            p[2] = __expf(fminf(lrelu(u0.z + d0.z), 60.f));
            p[3] = __expf(fminf(lrelu(u0.w + d0.w), 60.f));
            p[4] = __expf(fminf(lrelu(u1.x + d1.x), 60.f));
            p[5] = __expf(fminf(lrelu(u1.y + d1.y), 60.f));
            p[6] = __expf(fminf(lrelu(u1.z + d1.z), 60.f));
            p[7] = __expf(fminf(lrelu(u1.w + d1.w), 60.f));
        } else {
#pragma unroll
            for (int h = 0; h < 8; h++) p[h] = 0.f;
        }
#pragma unroll
        for (int h = 0; h < 8; h++) mypw[h * 64 + lane] = p[h];

        int cnt = min(64, r1 - base);
        for (int j = 0; j < cnt; j++) {
            int s = __shfl(s0, j, 64);
            float wA = mypw[hA * 64 + j];
            float wB = mypw[hB * 64 + j];
            ushort4 hvA = *reinterpret_cast<const ushort4*>(&h1b[s * 512 + cA]);
            ushort4 hvB = *reinterpret_cast<const ushort4*>(&h1b[s * 512 + cB]);
            sA += wA; sB += wB;
            accA[0] = fmaf(wA, bf2f(hvA.x), accA[0]);
            accA[1] = fmaf(wA, bf2f(hvA.y), accA[1]);
            accA[2] = fmaf(wA, bf2f(hvA.z), accA[2]);
            accA[3] = fmaf(wA, bf2f(hvA.w), accA[3]);
            accB[0] = fmaf(wB, bf2f(hvB.x), accB[0]);
            accB[1] = fmaf(wB, bf2f(hvB.y), accB[1]);
            accB[2] = fmaf(wB, bf2f(hvB.z), accB[2]);
            accB[3] = fmaf(wB, bf2f(hvB.w), accB[3]);
        }
    }
    float iA = 1.f / sA, iB = 1.f / sB;
    const float4 bA = *reinterpret_cast<const float4*>(&b1[cA]);
    const float4 bB = *reinterpret_cast<const float4*>(&b1[cB]);
    float vA[4], vB[4];
    vA[0] = accA[0] * iA + bA.x; vA[1] = accA[1] * iA + bA.y;
    vA[2] = accA[2] * iA + bA.z; vA[3] = accA[3] * iA + bA.w;
    vB[0] = accB[0] * iB + bB.x; vB[1] = accB[1] * iB + bB.y;
    vB[2] = accB[2] * iB + bB.z; vB[3] = accB[3] * iB + bB.w;
#pragma unroll
    for (int k = 0; k < 4; k++) {
        vA[k] = vA[k] > 0.f ? vA[k] : __expf(vA[k]) - 1.f;
        vB[k] = vB[k] > 0.f ? vB[k] : __expf(vB[k]) - 1.f;
    }
    ushort4 oA, oB;
    oA.x = f2bf(vA[0]); oA.y = f2bf(vA[1]); oA.z = f2bf(vA[2]); oA.w = f2bf(vA[3]);
    oB.x = f2bf(vB[0]); oB.y = f2bf(vB[1]); oB.z = f2bf(vB[2]); oB.w = f2bf(vB[3]);
    *reinterpret_cast<ushort4*>(&h1a[n * 512 + cA]) = oA;
    *reinterpret_cast<ushort4*>(&h1a[n * 512 + cB]) = oB;
}

/* ---------------- Layer 2 GEMM via MFMA: [N,512]@[512,16], bf16 input ---------------- */
__global__ __launch_bounds__(128) void k_gemm2(const unsigned short* __restrict__ h1a,
                                               const unsigned short* __restrict__ W2hiT,
                                               const unsigned short* __restrict__ W2loT,
                                               float* __restrict__ h2) {
    __shared__ unsigned short as_hi[32 * 520];
    const int t = threadIdx.x;
    const int rb = blockIdx.x * 32;

#pragma unroll
    for (int i = 0; i < 16; i++) {
        int idx = t + 128 * i;           /* 2048 16B-chunks */
        int r = idx >> 6;                /* 64 chunks per row */
        int k8 = (idx & 63) * 8;
        int gr = rb + r;
        uint4 v = make_uint4(0, 0, 0, 0);
        if (gr < N_NODES) v = *reinterpret_cast<const uint4*>(&h1a[gr * 512 + k8]);
        *reinterpret_cast<uint4*>(&as_hi[r * 520 + k8]) = v;
    }
    __syncthreads();

    const int lane = t & 63;
    const int w = t >> 6;
    const int col = lane & 15;
    const int kbase = (lane >> 4) * 8;
    const int arow = (w << 4) + (lane & 15);

    f32x4 acc = {0.f, 0.f, 0.f, 0.f};
#pragma unroll
    for (int kc = 0; kc < 16; kc++) {
        bf16x8 bh = *reinterpret_cast<const bf16x8*>(&W2hiT[col * 512 + kc * 32 + kbase]);
        bf16x8 bl = *reinterpret_cast<const bf16x8*>(&W2loT[col * 512 + kc * 32 + kbase]);
        bf16x8 ah = *reinterpret_cast<const bf16x8*>(&as_hi[arow * 520 + kc * 32 + kbase]);
        acc = __builtin_amdgcn_mfma_f32_16x16x32_bf16(ah, bh, acc, 0, 0, 0);
        acc = __builtin_amdgcn_mfma_f32_16x16x32_bf16(ah, bl, acc, 0, 0, 0);
    }
    const int r0 = rb + (w << 4) + (lane >> 4) * 4;
#pragma unroll
    for (int r = 0; r < 4; r++) {
        int row = r0 + r;
        if (row < N_NODES) h2[row * 16 + col] = acc[r];
    }
}

/* ---------------- attention halves, layer 2 ---------------- */
__global__ __launch_bounds__(256) void k_att2(const float* __restrict__ h2,
                                              const float* __restrict__ a2s,
                                              const float* __restrict__ a2d,
                                              float* __restrict__ al2s,
                                              float* __restrict__ al2d) {
    int n = blockIdx.x * blockDim.x + threadIdx.x;
    if (n >= N_NODES) return;
    float ps = 0.f, pd = 0.f;
#pragma unroll
    for (int j = 0; j < 16; j++) {
        float v = h2[n * 16 + j];
        ps = fmaf(v, a2s[j], ps);
        pd = fmaf(v, a2d[j], pd);
    }
    al2s[n] = ps;
    al2d[n] = pd;
}

/* ---------------- Layer 2: softmax + aggregation + bias -> out ---------------- */
__global__ __launch_bounds__(256) void k_agg2(const int* __restrict__ rowptr,
                                              const int* __restrict__ colsrc,
                                              const float* __restrict__ al2s,
                                              const float* __restrict__ al2d,
                                              const float* __restrict__ h2,
                                              const float* __restrict__ b2,
                                              float* __restrict__ out) {
    int wid = threadIdx.x >> 6, lane = threadIdx.x & 63;
    int n = blockIdx.x * 4 + wid;
    if (n >= N_NODES) return;
    int r0 = rowptr[n], r1 = rowptr[n + 1];
    float ald = al2d[n];
    float sm = 0.f;
    for (int e = r0 + lane; e < r1; e += 64)
        sm += __expf(fminf(lrelu(al2s[colsrc[e]] + ald), 60.f));
#pragma unroll
    for (int off = 32; off; off >>= 1) sm += __shfl_xor(sm, off, 64);
    float inv = 1.f / sm;
    int c = lane & 15, q = lane >> 4;
    float acc = 0.f;
    for (int e = r0 + q; e < r1; e += 4) {
        int s = colsrc[e];
        float w = __expf(fminf(lrelu(al2s[s] + ald), 60.f)) * inv;
        acc = fmaf(w, h2[s * 16 + c], acc);
    }
    acc += __shfl_xor(acc, 16, 64);
    acc += __shfl_xor(acc, 32, 64);
    if (q == 0) out[n * 16 + c] = acc + b2[c];
}

/* ---------------- launch ---------------- */
extern "C" void kernel_launch(void* const* d_in, const int* in_sizes, int n_in,
                              void* d_out, int out_size, void* d_ws, size_t ws_size,
                              hipStream_t stream) {
    const float* x   = (const float*)d_in[0];
    const int*   ei  = (const int*)d_in[1];
    const float* W1  = (const float*)d_in[2];
    const float* a1s = (const float*)d_in[3];
    const float* a1d = (const float*)d_in[4];
    const float* b1  = (const float*)d_in[5];
    const float* W2  = (const float*)d_in[6];
    const float* a2s = (const float*)d_in[7];
    const float* a2d = (const float*)d_in[8];
    const float* b2  = (const float*)d_in[9];
    float* out = (float*)d_out;

    char* ws = (char*)d_ws;
    unsigned short* h1b = (unsigned short*)(ws + 0);            /* N*512 bf16 = 51.2 MB */
    unsigned short* h1a = (unsigned short*)(ws + 51200000);     /* N*512 bf16 = 51.2 MB */
    float* h2   = (float*)(ws + 102400000);    /* N*16 f32 */
    float* al1s = (float*)(ws + 105600000);    /* N*8 */
    float* al1d = (float*)(ws + 107200000);    /* N*8 */
    float* al2s = (float*)(ws + 108800000);    /* N */
    float* al2d = (float*)(ws + 109000000);    /* N */
    int* rowptr = (int*)(ws + 109200000);      /* N+1 */
    int* counts = (int*)(ws + 109400004);      /* N */
    int* cursor = (int*)(ws + 109600004);      /* N (contiguous after counts) */
    int* colsrc = (int*)(ws + 109800004);      /* N_TOT */
    int* bsums  = (int*)(ws + 111600004);      /* 49 */
    unsigned short* W1hiT = (unsigned short*)(ws + 111600256);  /* 512x128 bf16 */
    unsigned short* W1loT = (unsigned short*)(ws + 111731328);
    unsigned short* W2hiT = (unsigned short*)(ws + 111900000);  /* 16x512 bf16 */
    unsigned short* W2loT = (unsigned short*)(ws + 111920000);

    /* CSR build */
    k_zero<<<(2 * N_NODES + 255) / 256, 256, 0, stream>>>(counts, 2 * N_NODES);
    k_hist<<<(N_TOT + 255) / 256, 256, 0, stream>>>(ei, counts);
    k_scan1<<<49, 256, 0, stream>>>(counts, rowptr, bsums);
    k_scan2<<<1, 64, 0, stream>>>(bsums, 49);
    k_scan3<<<(N_NODES + 255) / 256, 256, 0, stream>>>(rowptr, bsums);
    k_scatter<<<(N_TOT + 255) / 256, 256, 0, stream>>>(ei, rowptr, cursor, colsrc);

    /* weight prep */
    k_prepW1<<<256, 256, 0, stream>>>(W1, W1hiT, W1loT);
    k_prepW2<<<32, 256, 0, stream>>>(W2, W2hiT, W2loT);

    /* layer 1 */
    k_gemm1<<<(N_NODES + 63) / 64, 256, 0, stream>>>(x, W1hiT, W1loT, h1b);
    k_att1<<<(N_NODES + 3) / 4, 256, 0, stream>>>(h1b, a1s, a1d, al1s, al1d);
    k_agg1<<<(N_NODES + 3) / 4, 256, 0, stream>>>(rowptr, colsrc, al1s, al1d, h1b, b1, h1a);

    /* layer 2 */
    k_gemm2<<<(N_NODES + 31) / 32, 128, 0, stream>>>(h1a, W2hiT, W2loT, h2);
    k_att2<<<(N_NODES + 255) / 256, 256, 0, stream>>>(h2, a2s, a2d, al2s, al2d);
    k_agg2<<<(N_NODES + 3) / 4, 256, 0, stream>>>(rowptr, colsrc, al2s, al2d, h2, b2, out);
}